// Round 12
// baseline (740.420 us; speedup 1.0000x reference)
//
#include <hip/hip_runtime.h>
#include <math.h>

#define N_TOK 8192
#define DIM 1024
#define FF 4096
#define NE 8
#define SLOT_CAP (N_TOK*2 + NE*256)   // 18432
#define MAXT128 136

typedef float f32x4 __attribute__((ext_vector_type(4)));
typedef _Float16 f16x8 __attribute__((ext_vector_type(8)));
typedef unsigned int u32x4 __attribute__((ext_vector_type(4)));

__device__ __forceinline__ unsigned short f2h(float f) {
    _Float16 h = (_Float16)f;
    return __builtin_bit_cast(unsigned short, h);
}

// gelu (exact-erf form) via tanh identity; |err| ~2e-4 << fp16 rounding
__device__ __forceinline__ float fast_gelu(float v) {
    float u = v * v;
    float p = __builtin_fmaf(0.044715f, u, 1.0f);
    float y2 = v * p * 1.5957691216057308f;
    float ex = __expf(y2);
    float r = __builtin_amdgcn_rcpf(ex + 1.0f);
    return v - v * r;
}

__device__ __forceinline__ void gl_lds16(const void* g, void* l) {
    __builtin_amdgcn_global_load_lds(
        (const __attribute__((address_space(1))) void*)g,
        (__attribute__((address_space(3))) void*)l, 16, 0, 0);
}

__device__ __forceinline__ void vw6() { asm volatile("s_waitcnt vmcnt(6)"   ::: "memory"); }
__device__ __forceinline__ void vw0() { asm volatile("s_waitcnt vmcnt(0)"   ::: "memory"); }
__device__ __forceinline__ void lw0() { asm volatile("s_waitcnt lgkmcnt(0)" ::: "memory"); __builtin_amdgcn_sched_barrier(0); }
#define BAR __builtin_amdgcn_s_barrier()

// ================= router body (with fused count) =================
__device__ void router_body(char* smem, int rb,
    const float* __restrict__ x, const float* __restrict__ Wr,
    unsigned short* __restrict__ xh, int* __restrict__ ctl,
    int* __restrict__ tok2e, float* __restrict__ tok2w)
{
    float* wr = (float*)smem;
    __shared__ int hh[NE];
    const int t = threadIdx.x;
    if (t < NE) hh[t] = 0;
#pragma unroll
    for (int i = 0; i < (NE * DIM) / 256; ++i) wr[i * 256 + t] = Wr[i * 256 + t];
    __syncthreads();

    const int lane = t & 63;
    const int n = rb * 4 + (t >> 6);
    const float* xr = x + (size_t)n * DIM;
    unsigned short* xhr = xh + (size_t)n * DIM;

    float acc[NE];
#pragma unroll
    for (int e = 0; e < NE; ++e) acc[e] = 0.f;
#pragma unroll
    for (int j = 0; j < DIM / 64; ++j) {
        int d = j * 64 + lane;
        float v = xr[d];
        xhr[d] = f2h(v);
#pragma unroll
        for (int e = 0; e < NE; ++e) acc[e] += v * wr[e * DIM + d];
    }
#pragma unroll
    for (int off = 32; off >= 1; off >>= 1) {
#pragma unroll
        for (int e = 0; e < NE; ++e) acc[e] += __shfl_xor(acc[e], off);
    }
    if (lane == 0) {
        int e0 = 0; float v0 = acc[0];
#pragma unroll
        for (int e = 1; e < NE; ++e) if (acc[e] > v0) { v0 = acc[e]; e0 = e; }
        int e1 = -1; float v1 = -1e30f;
#pragma unroll
        for (int e = 0; e < NE; ++e) if (e != e0 && acc[e] > v1) { v1 = acc[e]; e1 = e; }
        float tt = expf(v1 - v0);
        tok2e[2 * n] = e0; tok2e[2 * n + 1] = e1;
        tok2w[2 * n] = 1.f / (1.f + tt); tok2w[2 * n + 1] = tt / (1.f + tt);
        atomicAdd(&hh[e0], 1);
        atomicAdd(&hh[e1], 1);
    }
    __syncthreads();
    if (t < NE && hh[t] > 0) atomicAdd(&ctl[t], hh[t]);
}

// ================= wcvt body: fp32 [E][KD][ND] -> fp16 planes [p][n][32] swizzled =================
__device__ void wcvt_body(char* smem, int cb,
    const float* __restrict__ W, unsigned short* __restrict__ Wt, int KD, int ND)
{
    unsigned short (*Lt)[72] = (unsigned short (*)[72])smem;
    const int t = threadIdx.x;
    const int nxb = ND >> 6, ktb = KD >> 6;
    const int e = cb / (nxb * ktb);
    const int rem = cb - e * nxb * ktb;
    const int kt = rem / nxb;
    const int n0 = (rem - kt * nxb) << 6;
    const float* src = W + (size_t)e * KD * ND + (size_t)(kt * 64) * ND + n0;
#pragma unroll
    for (int i = 0; i < 4; ++i) {
        int kl = (t >> 4) + i * 16;
        f32x4 v = *reinterpret_cast<const f32x4*>(src + (size_t)kl * ND + (t & 15) * 4);
        int h = kl >> 5, c = (kl >> 3) & 3, j = kl & 7;
#pragma unroll
        for (int m = 0; m < 4; ++m) {
            int nl = (t & 15) * 4 + m;
            Lt[nl][h * 32 + ((c ^ ((nl >> 1) & 3)) << 3) + j] = f2h(v[m]);
        }
    }
    __syncthreads();
    const int nl = t >> 2, qq = t & 3;
#pragma unroll
    for (int h = 0; h < 2; ++h) {
        unsigned short* dst = Wt + ((size_t)(e * ktb + kt) * 2 + h) * ((size_t)ND * 32)
                            + (size_t)(n0 + nl) * 32 + qq * 8;
        *reinterpret_cast<u32x4*>(dst) = *reinterpret_cast<const u32x4*>(&Lt[nl][h * 32 + qq * 8]);
    }
}

// ================= GEMM body: 128x256 tile, 4 waves, acc 4x8, BK=32, 2-buf =================
// PHASE 1: gate*gelu(X@W1) -> H2 plane-fmt. PHASE 2: H2@W2 -> atomicAdd(out), z-split.
template <int PHASE>
__device__ void gemm_body(char* lds, int bid, int zz,
    const unsigned short* __restrict__ Asrc, const unsigned short* __restrict__ Bh,
    unsigned short* __restrict__ Hout, float* __restrict__ Out,
    const int* __restrict__ ctl, const int* __restrict__ tos,
    const float* __restrict__ gos)
{
    constexpr int KD    = (PHASE == 1) ? DIM : FF;
    constexpr int ND    = (PHASE == 1) ? FF : DIM;
    constexpr int KTALL = KD / 32;
    constexpr int KT    = (PHASE == 1) ? KTALL : KTALL / 2;
    constexpr int NX    = ND / 256;                 // 16 / 4 (pow2)
    constexpr int BUFB  = 24576;                    // A 8K + B 16K

    // bijective XCD remap: each XCD sweeps N-tiles of its M-tiles
    const int xcd = bid & 7, chunk = bid >> 3;
    const int xp = chunk & (NX - 1);
    const int yp = (chunk / NX) * 8 + xcd;
    if (yp >= ctl[33]) return;
    const int e  = ctl[184 + yp];
    const int m0 = ctl[320 + yp];
    const int n0 = xp * 256;
    const int kt0 = (PHASE == 2) ? zz * KT : 0;

    const int t = threadIdx.x, l = t & 63, w = t >> 6;
    const int wm = w >> 1, wn = w & 1;               // 2x2 waves; wave tile 64x128
    const int fr = l & 15, hi = l >> 4;

    // A staging sources (2 gl_lds/thread/tile)
    const char* pa0; const char* pa1;
    if constexpr (PHASE == 1) {
        const int swz = ((l & 3) ^ ((l >> 3) & 3)) << 4;
        pa0 = (const char*)Asrc + (size_t)tos[m0 + w * 32 + (l >> 2)]      * 2048 + swz;
        pa1 = (const char*)Asrc + (size_t)tos[m0 + w * 32 + 16 + (l >> 2)] * 2048 + swz;
    } else {
        pa0 = (const char*)Asrc + (size_t)kt0 * (SLOT_CAP * 64)
            + (size_t)m0 * 64 + w * 2048 + l * 16;
        pa1 = pa0 + 1024;
    }
    // B staging source (4 gl_lds/thread/tile); plane p = e*KTALL + kt0 + ktt
    const char* pb = (const char*)Bh + ((size_t)(e * KTALL + kt0)) * ((size_t)ND * 64)
                   + (size_t)n0 * 64 + w * 4096 + l * 16;

    auto STAGE = [&](int ktt, int boff) {
        char* da = lds + boff + w * 2048;
        char* db = lds + boff + 8192 + w * 4096;
        if constexpr (PHASE == 1) {
            gl_lds16(pa0 + ktt * 64, da);
            gl_lds16(pa1 + ktt * 64, da + 1024);
        } else {
            const char* s0 = pa0 + (size_t)ktt * (SLOT_CAP * 64);
            gl_lds16(s0, da);
            gl_lds16(s0 + 1024, da + 1024);
        }
        const char* sb = pb + (size_t)ktt * ((size_t)ND * 64);
        gl_lds16(sb, db);
        gl_lds16(sb + 1024, db + 1024);
        gl_lds16(sb + 2048, db + 2048);
        gl_lds16(sb + 3072, db + 3072);
    };

    // ds_read bases; swizzle key (row>>1)&3 (measured conflict-free)
    const int key = (fr >> 1) & 3;
    const int A0 = (wm * 64 + fr) * 64 + ((hi ^ key) << 4);
    const int B0 = 8192 + (wn * 128 + fr) * 64 + ((hi ^ key) << 4);

    f16x8 af[4], bf[8];
    f32x4 acc[4][8];
#pragma unroll
    for (int a = 0; a < 4; ++a)
#pragma unroll
        for (int b = 0; b < 8; ++b) acc[a][b] = f32x4{0.f, 0.f, 0.f, 0.f};

    auto LDFRAG = [&](int boff) {
        const char* ba = lds + boff + A0;
        const char* bb = lds + boff + B0;
#pragma unroll
        for (int i = 0; i < 4; ++i) af[i] = *(const f16x8*)(ba + i * 1024);
#pragma unroll
        for (int i = 0; i < 8; ++i) bf[i] = *(const f16x8*)(bb + i * 1024);
    };
    auto MMS = [&]() {
#pragma unroll
        for (int mi = 0; mi < 4; ++mi)
#pragma unroll
            for (int ni = 0; ni < 8; ++ni)
                acc[mi][ni] = __builtin_amdgcn_mfma_f32_16x16x32_f16(
                    af[mi], bf[ni], acc[mi][ni], 0, 0, 0);
    };

    // prologue: stage tiles 0,1; vw6 => tile0 landed (tile1's 6 loads in flight)
    STAGE(0, 0); STAGE(1, BUFB);
    vw6(); BAR;
    int cur = 0;

    for (int kt = 0; kt < KT - 2; ++kt) {
        LDFRAG(cur);                        // 12 ds_read_b128, tile kt
        lw0();                              // frags in regs
        BAR;                                // all waves done reading buf cur
        STAGE(kt + 2, cur);                 // 6 loads -> buf cur
        MMS();                              // 32 MFMA overlap DMA
        vw6();                              // tile kt+1 landed (kt+2 in flight)
        BAR;
        cur ^= BUFB;
    }
    // tile KT-2 (no further staging)
    LDFRAG(cur); lw0(); MMS();
    vw0(); BAR;
    cur ^= BUFB;
    // tile KT-1
    LDFRAG(cur); lw0(); MMS();

    // epilogue
#pragma unroll
    for (int mi = 0; mi < 4; ++mi) {
#pragma unroll
        for (int rr = 0; rr < 4; ++rr) {
            const int srow = m0 + wm * 64 + mi * 16 + hi * 4 + rr;
            if constexpr (PHASE == 1) {
                const float gate = gos[srow];
#pragma unroll
                for (int ni = 0; ni < 8; ++ni) {
                    int col = n0 + wn * 128 + ni * 16 + fr;
                    float g = gate * fast_gelu(acc[mi][ni][rr]);
                    int p = col >> 5, c2 = (col >> 3) & 3, j2 = col & 7;
                    Hout[((size_t)p * SLOT_CAP + srow) * 32 +
                         ((c2 ^ ((srow >> 1) & 3)) << 3) + j2] = f2h(g);
                }
            } else {
                int tok = tos[srow];
                float* orow = Out + (size_t)tok * DIM + n0 + wn * 128 + fr;
#pragma unroll
                for (int ni = 0; ni < 8; ++ni)
                    atomicAdd(&orow[ni * 16], acc[mi][ni][rr]);
            }
        }
    }
}

// ================= kernels =================
// fuse1: router(+count) [0,2048) | wcvt W1 [2048, 2048+8192)
__global__ __launch_bounds__(256) void k_fuse1(
    const float* __restrict__ x, const float* __restrict__ Wr,
    unsigned short* __restrict__ xh, int* __restrict__ ctl,
    int* __restrict__ tok2e, float* __restrict__ tok2w,
    const float* __restrict__ W1, unsigned short* __restrict__ Wt1)
{
    __shared__ __align__(16) char smem[32768];
    const int b = blockIdx.x;
    if (b < 2048) router_body(smem, b, x, Wr, xh, ctl, tok2e, tok2w);
    else          wcvt_body(smem, b - 2048, W1, Wt1, DIM, FF);
}

// fuse2: gemm1 [0,2176) | wcvt W2 [2176, 2176+8192)
__global__ __launch_bounds__(256) void k_fuse2(
    const unsigned short* __restrict__ xh, const unsigned short* __restrict__ Wt1,
    unsigned short* __restrict__ H2, const int* __restrict__ ctl,
    const int* __restrict__ tos, const float* __restrict__ gos,
    const float* __restrict__ W2, unsigned short* __restrict__ Wt2)
{
    __shared__ __align__(1024) char smem[49152];
    const int b = blockIdx.x;
    if (b < 2176) gemm_body<1>(smem, b, 0, xh, Wt1, H2, nullptr, ctl, tos, gos);
    else          wcvt_body(smem, b - 2176, W2, Wt2, FF, DIM);
}

__global__ __launch_bounds__(256) void k_g1(
    const unsigned short* __restrict__ xh, const unsigned short* __restrict__ Wt1,
    unsigned short* __restrict__ H2, const int* __restrict__ ctl,
    const int* __restrict__ tos, const float* __restrict__ gos)
{
    __shared__ __align__(1024) char smem[49152];
    gemm_body<1>(smem, blockIdx.x, 0, xh, Wt1, H2, nullptr, ctl, tos, gos);
}

__global__ __launch_bounds__(256) void k_wcvt2(
    const float* __restrict__ W2, unsigned short* __restrict__ Wt)
{
    __shared__ __align__(16) char smem[16384];
    wcvt_body(smem, blockIdx.x, W2, Wt, FF, DIM);
}

__global__ __launch_bounds__(256) void k_g2(
    const unsigned short* __restrict__ H2, const unsigned short* __restrict__ Wt,
    float* __restrict__ Out, const int* __restrict__ ctl,
    const int* __restrict__ tos, const float* __restrict__ gos)
{
    __shared__ __align__(1024) char smem[49152];
    gemm_body<2>(smem, blockIdx.x, blockIdx.y, H2, Wt, nullptr, Out, ctl, tos, gos);
}

// ---------------- Setup: 256-padded offsets, tile maps, parallel pad fill ----------------
__global__ __launch_bounds__(256) void k_setup(
    int* __restrict__ ctl, int* __restrict__ tos, float* __restrict__ gos)
{
    __shared__ int sh[NE * 2];
    const int t = threadIdx.x;
    if (t == 0) {
        int run = 0, T = 0, T128 = 0;
        for (int e = 0; e < NE; ++e) {
            ctl[16 + e] = run;
            int c = ctl[e];
            sh[e] = run; sh[NE + e] = c;
            int mt = (c + 255) >> 8;
            for (int j = 0; j < mt; ++j) { ctl[40 + T] = e; ctl[112 + T] = run + j * 256; ++T; }
            int mt128 = (c + 127) >> 7;
            for (int j = 0; j < mt128; ++j) { ctl[184 + T128] = e; ctl[320 + T128] = run + j * 128; ++T128; }
            run += mt * 256;
        }
        ctl[16 + NE] = run;
        ctl[32] = T; ctl[33] = T128;
    }
    __syncthreads();
    for (int e = 0; e < NE; ++e) {
        int off = sh[e], c = sh[NE + e];
        int pad = ((c + 255) >> 8) << 8;
        for (int s = c + t; s < pad; s += 256) { tos[off + s] = 0; gos[off + s] = 0.f; }
    }
}

// ---------------- Scatter ----------------
__global__ __launch_bounds__(256) void k_scatter(
    const int* __restrict__ tok2e, const float* __restrict__ tok2w,
    int* __restrict__ ctl, int* __restrict__ tos, float* __restrict__ gos)
{
    __shared__ int h[NE], base[NE];
    const int t = threadIdx.x;
    if (t < NE) h[t] = 0;
    __syncthreads();
    const int n = blockIdx.x * 256 + t;
    const int e0 = tok2e[2 * n], e1 = tok2e[2 * n + 1];
    const int p0 = atomicAdd(&h[e0], 1);
    const int p1 = atomicAdd(&h[e1], 1);
    __syncthreads();
    if (t < NE) base[t] = ctl[16 + t] + atomicAdd(&ctl[8 + t], h[t]);
    __syncthreads();
    const int s0 = base[e0] + p0, s1 = base[e1] + p1;
    tos[s0] = n; gos[s0] = tok2w[2 * n];
    tos[s1] = n; gos[s1] = tok2w[2 * n + 1];
}

// ---------------- launch ----------------
extern "C" void kernel_launch(void* const* d_in, const int* in_sizes, int n_in,
                              void* d_out, int out_size, void* d_ws, size_t ws_size,
                              hipStream_t stream) {
    (void)in_sizes; (void)n_in;
    const float* x  = (const float*)d_in[0];
    const float* Wr = (const float*)d_in[1];
    const float* W1 = (const float*)d_in[2];
    const float* W2 = (const float*)d_in[3];
    float* out = (float*)d_out;
    char* ws = (char*)d_ws;

    // ws layout (bytes): ctl@0, tok2e@4096, tok2w@69632, tos@135168, gos@208896,
    //   xh fp16 @282624 (16MB)          -> 17,059,840
    //   H2 fp16 plane-fmt (151MB)       -> 168,054,784
    //   Wt1 fp16 (67MB)                 -> 235,163,648
    //   Wt2 fp16 (67MB, optional)       -> 302,272,512
    const size_t NEED_FULL  = 235163648ULL;
    const size_t NEED_FULL2 = 302272512ULL;
    if (ws_size < NEED_FULL) return;
    const bool big2 = ws_size >= NEED_FULL2;

    int*            ctl = (int*)(ws + 0);
    int*            t2e = (int*)(ws + 4096);
    float*          t2w = (float*)(ws + 69632);
    int*            tos = (int*)(ws + 135168);
    float*          gos = (float*)(ws + 208896);
    unsigned short* xh  = (unsigned short*)(ws + 282624);
    unsigned short* H2  = (unsigned short*)(ws + 17059840);
    unsigned short* Wt1 = (unsigned short*)(ws + 168054784);
    unsigned short* Wt2 = big2 ? (unsigned short*)(ws + 235163648) : Wt1;

    hipMemsetAsync(ctl, 0, 64, stream);
    hipMemsetAsync(d_out, 0, (size_t)out_size * 4, stream);

    k_fuse1 <<<dim3(2048 + 8192), dim3(256), 0, stream>>>(x, Wr, xh, ctl, t2e, t2w, W1, Wt1);
    k_setup <<<dim3(1), dim3(256), 0, stream>>>(ctl, tos, gos);
    k_scatter<<<dim3(N_TOK / 256), dim3(256), 0, stream>>>(t2e, t2w, ctl, tos, gos);

    if (big2) {
        k_fuse2<<<dim3(2176 + 8192), dim3(256), 0, stream>>>(
            xh, Wt1, H2, ctl, tos, gos, W2, Wt2);
    } else {
        k_g1<<<dim3(2176), dim3(256), 0, stream>>>(xh, Wt1, H2, ctl, tos, gos);
        k_wcvt2<<<dim3(8192), dim3(256), 0, stream>>>(W2, Wt1);
    }
    k_g2<<<dim3(544, 2), dim3(256), 0, stream>>>(H2, Wt2, out, ctl, tos, gos);
}

// Round 13
// 549.111 us; speedup vs baseline: 1.3484x; 1.3484x over previous
//
#include <hip/hip_runtime.h>
#include <math.h>

#define N_TOK 8192
#define DIM 1024
#define FF 4096
#define NE 8
#define SLOT_CAP (N_TOK*2 + NE*256)   // 18432
#define MAXT128 136

typedef float f32x4 __attribute__((ext_vector_type(4)));
typedef _Float16 f16x8 __attribute__((ext_vector_type(8)));
typedef unsigned int u32x4 __attribute__((ext_vector_type(4)));

__device__ __forceinline__ unsigned short f2h(float f) {
    _Float16 h = (_Float16)f;
    return __builtin_bit_cast(unsigned short, h);
}

// gelu (exact-erf form) via tanh identity; |err| ~2e-4 << fp16 rounding
__device__ __forceinline__ float fast_gelu(float v) {
    float u = v * v;
    float p = __builtin_fmaf(0.044715f, u, 1.0f);
    float y2 = v * p * 1.5957691216057308f;
    float ex = __expf(y2);
    float r = __builtin_amdgcn_rcpf(ex + 1.0f);
    return v - v * r;
}

__device__ __forceinline__ void gl_lds16(const void* g, void* l) {
    __builtin_amdgcn_global_load_lds(
        (const __attribute__((address_space(1))) void*)g,
        (__attribute__((address_space(3))) void*)l, 16, 0, 0);
}

__device__ __forceinline__ void vw8() { asm volatile("s_waitcnt vmcnt(8)"   ::: "memory"); }
__device__ __forceinline__ void vw4() { asm volatile("s_waitcnt vmcnt(4)"   ::: "memory"); }
__device__ __forceinline__ void vw0() { asm volatile("s_waitcnt vmcnt(0)"   ::: "memory"); }
__device__ __forceinline__ void lw0() { asm volatile("s_waitcnt lgkmcnt(0)" ::: "memory"); __builtin_amdgcn_sched_barrier(0); }
#define BAR __builtin_amdgcn_s_barrier()

// ================= router body (fused per-block count) =================
__device__ void router_body(char* smem, int rb,
    const float* __restrict__ x, const float* __restrict__ Wr,
    unsigned short* __restrict__ xh, int* __restrict__ ctl,
    int* __restrict__ tok2e, float* __restrict__ tok2w)
{
    float* wr = (float*)smem;
    __shared__ int hh[NE];
    const int t = threadIdx.x;
    if (t < NE) hh[t] = 0;
#pragma unroll
    for (int i = 0; i < (NE * DIM) / 256; ++i) wr[i * 256 + t] = Wr[i * 256 + t];
    __syncthreads();

    const int lane = t & 63;
    const int n = rb * 4 + (t >> 6);
    const float* xr = x + (size_t)n * DIM;
    unsigned short* xhr = xh + (size_t)n * DIM;

    float acc[NE];
#pragma unroll
    for (int e = 0; e < NE; ++e) acc[e] = 0.f;
#pragma unroll
    for (int j = 0; j < DIM / 64; ++j) {
        int d = j * 64 + lane;
        float v = xr[d];
        xhr[d] = f2h(v);
#pragma unroll
        for (int e = 0; e < NE; ++e) acc[e] += v * wr[e * DIM + d];
    }
#pragma unroll
    for (int off = 32; off >= 1; off >>= 1) {
#pragma unroll
        for (int e = 0; e < NE; ++e) acc[e] += __shfl_xor(acc[e], off);
    }
    if (lane == 0) {
        int e0 = 0; float v0 = acc[0];
#pragma unroll
        for (int e = 1; e < NE; ++e) if (acc[e] > v0) { v0 = acc[e]; e0 = e; }
        int e1 = -1; float v1 = -1e30f;
#pragma unroll
        for (int e = 0; e < NE; ++e) if (e != e0 && acc[e] > v1) { v1 = acc[e]; e1 = e; }
        float tt = expf(v1 - v0);
        tok2e[2 * n] = e0; tok2e[2 * n + 1] = e1;
        tok2w[2 * n] = 1.f / (1.f + tt); tok2w[2 * n + 1] = tt / (1.f + tt);
        atomicAdd(&hh[e0], 1);
        atomicAdd(&hh[e1], 1);
    }
    __syncthreads();
    if (t < NE && hh[t] > 0) atomicAdd(&ctl[t], hh[t]);
}

// ================= wcvt body: fp32 [E][KD][ND] -> fp16 planes [p][n][32] swizzled =================
__device__ void wcvt_body(char* smem, int cb,
    const float* __restrict__ W, unsigned short* __restrict__ Wt, int KD, int ND)
{
    unsigned short (*Lt)[72] = (unsigned short (*)[72])smem;
    const int t = threadIdx.x;
    const int nxb = ND >> 6, ktb = KD >> 6;
    const int e = cb / (nxb * ktb);
    const int rem = cb - e * nxb * ktb;
    const int kt = rem / nxb;
    const int n0 = (rem - kt * nxb) << 6;
    const float* src = W + (size_t)e * KD * ND + (size_t)(kt * 64) * ND + n0;
#pragma unroll
    for (int i = 0; i < 4; ++i) {
        int kl = (t >> 4) + i * 16;
        f32x4 v = *reinterpret_cast<const f32x4*>(src + (size_t)kl * ND + (t & 15) * 4);
        int h = kl >> 5, c = (kl >> 3) & 3, j = kl & 7;
#pragma unroll
        for (int m = 0; m < 4; ++m) {
            int nl = (t & 15) * 4 + m;
            Lt[nl][h * 32 + ((c ^ ((nl >> 1) & 3)) << 3) + j] = f2h(v[m]);
        }
    }
    __syncthreads();
    const int nl = t >> 2, qq = t & 3;
#pragma unroll
    for (int h = 0; h < 2; ++h) {
        unsigned short* dst = Wt + ((size_t)(e * ktb + kt) * 2 + h) * ((size_t)ND * 32)
                            + (size_t)(n0 + nl) * 32 + qq * 8;
        *reinterpret_cast<u32x4*>(dst) = *reinterpret_cast<const u32x4*>(&Lt[nl][h * 32 + qq * 8]);
    }
}

// fuse1: router(+count) [0,2048) | wcvt W1 [2048, 2048+8192)
__global__ __launch_bounds__(256) void k_fuse1(
    const float* __restrict__ x, const float* __restrict__ Wr,
    unsigned short* __restrict__ xh, int* __restrict__ ctl,
    int* __restrict__ tok2e, float* __restrict__ tok2w,
    const float* __restrict__ W1, unsigned short* __restrict__ Wt1)
{
    __shared__ __align__(16) char smem[32768];
    const int b = blockIdx.x;
    if (b < 2048) router_body(smem, b, x, Wr, xh, ctl, tok2e, tok2w);
    else          wcvt_body(smem, b - 2048, W1, Wt1, DIM, FF);
}

__global__ __launch_bounds__(256) void k_wcvt2(
    const float* __restrict__ W2, unsigned short* __restrict__ Wt)
{
    __shared__ __align__(16) char smem[16384];
    wcvt_body(smem, blockIdx.x, W2, Wt, FF, DIM);
}

// ---------------- Setup: padded offsets, tile maps, parallel pad fill ----------------
__global__ __launch_bounds__(256) void k_setup(
    int* __restrict__ ctl, int* __restrict__ tos, float* __restrict__ gos)
{
    __shared__ int sh[NE * 2];
    const int t = threadIdx.x;
    if (t == 0) {
        int run = 0, T = 0, T128 = 0;
        for (int e = 0; e < NE; ++e) {
            ctl[16 + e] = run;
            int c = ctl[e];
            sh[e] = run; sh[NE + e] = c;
            int mt = (c + 255) >> 8;
            for (int j = 0; j < mt; ++j) { ctl[40 + T] = e; ctl[112 + T] = run + j * 256; ++T; }
            int mt128 = (c + 127) >> 7;
            for (int j = 0; j < mt128; ++j) { ctl[184 + T128] = e; ctl[320 + T128] = run + j * 128; ++T128; }
            run += mt * 256;
        }
        ctl[16 + NE] = run;
        ctl[32] = T; ctl[33] = T128;
    }
    __syncthreads();
    for (int e = 0; e < NE; ++e) {
        int off = sh[e], c = sh[NE + e];
        int pad = ((c + 255) >> 8) << 8;
        for (int s = c + t; s < pad; s += 256) { tos[off + s] = 0; gos[off + s] = 0.f; }
    }
}

// ---------------- Scatter ----------------
__global__ __launch_bounds__(256) void k_scatter(
    const int* __restrict__ tok2e, const float* __restrict__ tok2w,
    int* __restrict__ ctl, int* __restrict__ tos, float* __restrict__ gos)
{
    __shared__ int h[NE], base[NE];
    const int t = threadIdx.x;
    if (t < NE) h[t] = 0;
    __syncthreads();
    const int n = blockIdx.x * 256 + t;
    const int e0 = tok2e[2 * n], e1 = tok2e[2 * n + 1];
    const int p0 = atomicAdd(&h[e0], 1);
    const int p1 = atomicAdd(&h[e1], 1);
    __syncthreads();
    if (t < NE) base[t] = ctl[16 + t] + atomicAdd(&ctl[8 + t], h[t]);
    __syncthreads();
    const int s0 = base[e0] + p0, s1 = base[e1] + p1;
    tos[s0] = n; gos[s0] = tok2w[2 * n];
    tos[s1] = n; gos[s1] = tok2w[2 * n + 1];
}

// ---- fragment / mfma macros (static register sets X/Y) ----
#define LDF(SET, BOFF) do {                                                   \
    const char* ba_ = lds + (BOFF) + A0;                                      \
    const char* bb_ = lds + (BOFF) + 8192 + B0;                               \
    _Pragma("unroll")                                                         \
    for (int i_ = 0; i_ < 4; ++i_) af##SET[i_] = *(const f16x8*)(ba_ + i_ * 1024); \
    _Pragma("unroll")                                                         \
    for (int i_ = 0; i_ < 4; ++i_) bf##SET[i_] = *(const f16x8*)(bb_ + i_ * 1024); \
} while (0)

#define MMS(SET) do {                                                         \
    _Pragma("unroll")                                                         \
    for (int mi_ = 0; mi_ < 4; ++mi_)                                         \
        _Pragma("unroll")                                                     \
        for (int ni_ = 0; ni_ < 4; ++ni_)                                     \
            acc[mi_][ni_] = __builtin_amdgcn_mfma_f32_16x16x32_f16(           \
                af##SET[mi_], bf##SET[ni_], acc[mi_][ni_], 0, 0, 0);          \
} while (0)

// ---------------- 128x128 BK=32, 4-buf LDS, 2-round vmcnt slack ----------------
// iter i: BAR; STAGE(i+4 -> buf[i&3]); LDF(i+1); MFMA(i); lw0; vw8 (tile i+2 landed).
template <int PHASE>
__global__ __launch_bounds__(256) void k_g4(
    const unsigned short* __restrict__ Asrc, const unsigned short* __restrict__ Bh,
    unsigned short* __restrict__ Hout, float* __restrict__ Out,
    const int* __restrict__ ctl, const int* __restrict__ tos,
    const float* __restrict__ gos)
{
    constexpr int KD = (PHASE == 1) ? DIM : FF;
    constexpr int ND = (PHASE == 1) ? FF : DIM;
    constexpr int KT = KD / 32;                    // 32 / 128 (even)
    constexpr int NX = ND / 128;

    // bijective XCD remap: each XCD sweeps N-tiles of its M-tiles
    const int lin = blockIdx.y * NX + blockIdx.x;
    const int xcd = lin & 7, chunk = lin >> 3;
    const int xp = chunk & (NX - 1);
    const int yp = (chunk / NX) * 8 + xcd;
    if (yp >= ctl[33]) return;
    const int e  = ctl[184 + yp];
    const int m0 = ctl[320 + yp];
    const int n0 = xp * 128;

    __shared__ __align__(1024) char lds[4 * 16384];   // 4 bufs x (A 8K + B 8K)

    const int t = threadIdx.x, l = t & 63, w = t >> 6;
    const int wm = w >> 1, wn = w & 1;                 // 2x2 waves, 64x64 per wave
    const int fr = l & 15, hi = l >> 4;

    // staging sources (2 A + 2 B gl_lds per thread per tile)
    const char* pa0; const char* pa1; const char* pb;
    if constexpr (PHASE == 1) {
        const int swz = ((l & 3) ^ ((l >> 3) & 3)) << 4;   // pre-swizzled source chunk
        pa0 = (const char*)Asrc + (size_t)tos[m0 + w * 32 + (l >> 2)]      * 2048 + swz;
        pa1 = (const char*)Asrc + (size_t)tos[m0 + w * 32 + 16 + (l >> 2)] * 2048 + swz;
    } else {
        pa0 = (const char*)Asrc + (size_t)m0 * 64 + w * 2048 + l * 16;   // H2 pre-swizzled
        pa1 = pa0 + 1024;
    }
    pb = (const char*)Bh + (size_t)e * KD * ND * 2 + (size_t)n0 * 64 + w * 2048 + l * 16;

    auto STAGE = [&](int ktt, int boff) {
        char* da = lds + boff + w * 2048;
        char* db = lds + boff + 8192 + w * 2048;
        if constexpr (PHASE == 1) {
            gl_lds16(pa0 + ktt * 64, da);
            gl_lds16(pa1 + ktt * 64, da + 1024);
        } else {
            const char* s = pa0 + (size_t)ktt * (SLOT_CAP * 64);
            gl_lds16(s, da);
            gl_lds16(s + 1024, da + 1024);
        }
        const char* sb = pb + (size_t)ktt * (ND * 64);
        gl_lds16(sb, db);
        gl_lds16(sb + 1024, db + 1024);
    };

    // ds_read bases; swizzle key (row>>1)&3 (measured conflict-free)
    const int key = (fr >> 1) & 3;
    const int A0 = (wm * 64 + fr) * 64 + ((hi ^ key) << 4);
    const int B0 = (wn * 64 + fr) * 64 + ((hi ^ key) << 4);

    f16x8 afX[4], bfX[4], afY[4], bfY[4];
    f32x4 acc[4][4];
#pragma unroll
    for (int a = 0; a < 4; ++a)
#pragma unroll
        for (int b = 0; b < 4; ++b) acc[a][b] = f32x4{0.f, 0.f, 0.f, 0.f};

    // ---- prologue: stage tiles 0..3; vw8 => tiles 0,1 landed ----
    STAGE(0, 0); STAGE(1, 16384); STAGE(2, 32768); STAGE(3, 49152);
    vw8(); BAR;
    LDF(X, 0); lw0();

    // ---- steady pairs: iter i (X), iter i+1 (Y); stage i+4 / i+5 ----
    for (int i = 0; i < KT - 4; i += 2) {
        BAR; STAGE(i + 4, (i & 3) * 16384);       LDF(Y, ((i + 1) & 3) * 16384); MMS(X); lw0(); vw8();
        BAR; STAGE(i + 5, ((i + 1) & 3) * 16384); LDF(X, ((i + 2) & 3) * 16384); MMS(Y); lw0(); vw8();
    }
    // ---- drain: tiles KT-4 .. KT-1 (KT even => KT-4 in X) ----
    BAR; LDF(Y, ((KT - 3) & 3) * 16384); MMS(X); lw0(); vw4();
    BAR; LDF(X, ((KT - 2) & 3) * 16384); MMS(Y); lw0(); vw0();
    BAR; LDF(Y, ((KT - 1) & 3) * 16384); MMS(X); lw0();
    MMS(Y);

    // ---- epilogue ----
#pragma unroll
    for (int mi = 0; mi < 4; ++mi) {
#pragma unroll
        for (int rr = 0; rr < 4; ++rr) {
            const int srow = m0 + wm * 64 + mi * 16 + hi * 4 + rr;
            if constexpr (PHASE == 1) {
                const float gate = gos[srow];
#pragma unroll
                for (int ni = 0; ni < 4; ++ni) {
                    int col = n0 + wn * 64 + ni * 16 + fr;
                    float g = gate * fast_gelu(acc[mi][ni][rr]);
                    int p = col >> 5, c2 = (col >> 3) & 3, j2 = col & 7;
                    Hout[((size_t)p * SLOT_CAP + srow) * 32 +
                         ((c2 ^ ((srow >> 1) & 3)) << 3) + j2] = f2h(g);
                }
            } else {
                int tok = tos[srow];
                float* orow = Out + (size_t)tok * DIM + n0 + wn * 64 + fr;
#pragma unroll
                for (int ni = 0; ni < 4; ++ni)
                    atomicAdd(&orow[ni * 16], acc[mi][ni][rr]);
            }
        }
    }
}

// ---------------- Fallback 128-tile GEMM (reg-staged fp32 B; used if ws too small) ----------------
template <int PHASE>
__global__ __launch_bounds__(256) void k_gemm_fb(
    const unsigned short* __restrict__ Asrc, const float* __restrict__ Bf,
    unsigned short* __restrict__ Hout, float* __restrict__ Out,
    const int* __restrict__ ctl, const int* __restrict__ tos,
    const float* __restrict__ gos)
{
    constexpr int KD = (PHASE == 1) ? DIM : FF;
    constexpr int ND = (PHASE == 1) ? FF : DIM;
    constexpr int KT = KD / 64;

    const int tidx = blockIdx.y;
    if (tidx >= ctl[33]) return;
    const int e  = ctl[184 + tidx];
    const int m0 = ctl[320 + tidx];
    const int n0 = blockIdx.x * 128;

    __shared__ __align__(16) unsigned short Al[128 * 64];
    __shared__ __align__(16) unsigned short Bl[128 * 64];
    char* Alc = (char*)Al;
    char* Blc = (char*)Bl;

    const int t = threadIdx.x, lane = t & 63, wv = t >> 6;
    const int wm = wv >> 1, wn = wv & 1;

    const unsigned short* asrc[4];
    if (PHASE == 1) {
        const int swz = ((lane & 7) ^ (lane >> 3)) * 8;
#pragma unroll
        for (int i = 0; i < 4; ++i) {
            int row = i * 32 + wv * 8 + (lane >> 3);
            asrc[i] = Asrc + (size_t)tos[m0 + row] * KD + swz;
        }
    }
    const int lin = wv * 512 + lane * 8;

    f32x4 acc[4][4];
#pragma unroll
    for (int a = 0; a < 4; ++a)
#pragma unroll
        for (int b = 0; b < 4; ++b) acc[a][b] = f32x4{0.f, 0.f, 0.f, 0.f};

    for (int kt = 0; kt < KT; ++kt) {
        if (PHASE == 1) {
#pragma unroll
            for (int i = 0; i < 4; ++i)
                gl_lds16(asrc[i] + kt * 64, Al + i * 2048 + wv * 512);
        } else {
            const unsigned short* ab = Asrc + ((size_t)kt * SLOT_CAP + m0) * 64;
#pragma unroll
            for (int i = 0; i < 4; ++i)
                gl_lds16(ab + i * 2048 + lin, Al + i * 2048 + wv * 512);
        }
        {
            const float* Wf = Bf + (size_t)e * KD * ND;
            const int kb = (wv >> 1) * 32 + (lane >> 4) * 8;
            const int n4 = (wv & 1) * 64 + (lane & 15) * 4;
            f32x4 rr[8];
#pragma unroll
            for (int r2 = 0; r2 < 8; ++r2)
                rr[r2] = *reinterpret_cast<const f32x4*>(
                    Wf + (size_t)(kt * 64 + kb + r2) * ND + n0 + n4);
#pragma unroll
            for (int m = 0; m < 4; ++m) {
                f16x8 v;
#pragma unroll
                for (int r2 = 0; r2 < 8; ++r2) v[r2] = (_Float16)rr[r2][m];
                int nn = n4 + m;
                *reinterpret_cast<f16x8*>(Blc + nn * 128 + (((kb >> 3) ^ (nn & 7)) << 4)) = v;
            }
        }
        __syncthreads();
#pragma unroll
        for (int kc = 0; kc < 2; ++kc) {
            const int cb = kc * 4 + (lane >> 4);
            f16x8 af[4], bf[4];
#pragma unroll
            for (int mi = 0; mi < 4; ++mi) {
                int row = wm * 64 + mi * 16 + (lane & 15);
                af[mi] = *reinterpret_cast<const f16x8*>(Alc + row * 128 + ((cb ^ (row & 7)) << 4));
            }
#pragma unroll
            for (int ni = 0; ni < 4; ++ni) {
                int col = wn * 64 + ni * 16 + (lane & 15);
                bf[ni] = *reinterpret_cast<const f16x8*>(Blc + col * 128 + ((cb ^ (col & 7)) << 4));
            }
#pragma unroll
            for (int mi = 0; mi < 4; ++mi)
#pragma unroll
                for (int ni = 0; ni < 4; ++ni)
                    acc[mi][ni] = __builtin_amdgcn_mfma_f32_16x16x32_f16(
                        af[mi], bf[ni], acc[mi][ni], 0, 0, 0);
        }
        __syncthreads();
    }

#pragma unroll
    for (int mi = 0; mi < 4; ++mi) {
#pragma unroll
        for (int rr = 0; rr < 4; ++rr) {
            const int srow = m0 + wm * 64 + mi * 16 + (lane >> 4) * 4 + rr;
            if (PHASE == 1) {
                const float gate = gos[srow];
#pragma unroll
                for (int ni = 0; ni < 4; ++ni) {
                    int col = n0 + wn * 64 + ni * 16 + (lane & 15);
                    float g = gate * fast_gelu(acc[mi][ni][rr]);
                    int kl = col & 63;
                    Hout[((size_t)(col >> 6) * SLOT_CAP + srow) * 64 +
                         (((kl >> 3) ^ (srow & 7)) << 3) + (kl & 7)] = f2h(g);
                }
            } else {
                int tok = tos[srow];
                float* orow = Out + (size_t)tok * DIM + n0 + wn * 64 + (lane & 15);
#pragma unroll
                for (int ni = 0; ni < 4; ++ni)
                    atomicAdd(&orow[ni * 16], acc[mi][ni][rr]);
            }
        }
    }
}

// ---------------- launch ----------------
extern "C" void kernel_launch(void* const* d_in, const int* in_sizes, int n_in,
                              void* d_out, int out_size, void* d_ws, size_t ws_size,
                              hipStream_t stream) {
    (void)in_sizes; (void)n_in;
    const float* x  = (const float*)d_in[0];
    const float* Wr = (const float*)d_in[1];
    const float* W1 = (const float*)d_in[2];
    const float* W2 = (const float*)d_in[3];
    float* out = (float*)d_out;
    char* ws = (char*)d_ws;

    // ws layout (bytes): ctl@0, tok2e@4096, tok2w@69632, tos@135168, gos@208896,
    //   xh fp16 @282624 (16MB)          -> 17,059,840
    //   H2 fp16 plane-fmt (151MB)       -> 168,054,784
    //   Wt1 fp16 (67MB, reused for W2t) -> 235,163,648
    const size_t NEED_FB   = 168054784ULL;
    const size_t NEED_FULL = 235163648ULL;
    if (ws_size < NEED_FB) return;
    const bool big = ws_size >= NEED_FULL;

    int*            ctl = (int*)(ws + 0);
    int*            t2e = (int*)(ws + 4096);
    float*          t2w = (float*)(ws + 69632);
    int*            tos = (int*)(ws + 135168);
    float*          gos = (float*)(ws + 208896);
    unsigned short* xh  = (unsigned short*)(ws + 282624);
    unsigned short* H2  = (unsigned short*)(ws + 17059840);
    unsigned short* Wt  = (unsigned short*)(ws + 168054784);

    hipMemsetAsync(ctl, 0, 64, stream);
    hipMemsetAsync(d_out, 0, (size_t)out_size * 4, stream);

    if (big) {
        // router(+count) fused with wcvt(W1)
        k_fuse1 <<<dim3(2048 + 8192), dim3(256), 0, stream>>>(x, Wr, xh, ctl, t2e, t2w, W1, Wt);
        k_setup <<<dim3(1), dim3(256), 0, stream>>>(ctl, tos, gos);
        k_scatter<<<dim3(N_TOK / 256), dim3(256), 0, stream>>>(t2e, t2w, ctl, tos, gos);
        k_g4<1><<<dim3(FF / 128, MAXT128), dim3(256), 0, stream>>>(
            xh, Wt, H2, nullptr, ctl, tos, gos);
        k_wcvt2<<<dim3(8192), dim3(256), 0, stream>>>(W2, Wt);
        k_g4<2><<<dim3(DIM / 128, MAXT128), dim3(256), 0, stream>>>(
            H2, Wt, nullptr, out, ctl, tos, gos);
    } else {
        k_fuse1 <<<dim3(2048), dim3(256), 0, stream>>>(x, Wr, xh, ctl, t2e, t2w, nullptr, nullptr);
        k_setup <<<dim3(1), dim3(256), 0, stream>>>(ctl, tos, gos);
        k_scatter<<<dim3(N_TOK / 256), dim3(256), 0, stream>>>(t2e, t2w, ctl, tos, gos);
        k_gemm_fb<1><<<dim3(FF / 128, MAXT128), dim3(256), 0, stream>>>(
            xh, W1, H2, nullptr, ctl, tos, gos);
        k_gemm_fb<2><<<dim3(DIM / 128, MAXT128), dim3(256), 0, stream>>>(
            H2, W2, nullptr, out, ctl, tos, gos);
    }
}